// Round 1
// baseline (362.744 us; speedup 1.0000x reference)
//
#include <hip/hip_runtime.h>
#include <stdint.h>

// ---- types ----
typedef __bf16 bf16x8 __attribute__((ext_vector_type(8)));
typedef float  f32x4  __attribute__((ext_vector_type(4)));
typedef unsigned int u32x4 __attribute__((ext_vector_type(4)));
typedef unsigned short u16;

__device__ __forceinline__ u16 f2bf(float f) {
    union { float f; unsigned u; } v; v.f = f;
    unsigned r = v.u + 0x7fffu + ((v.u >> 16) & 1u);
    return (u16)(r >> 16);
}

__device__ __forceinline__ bf16x8 ld_frag(const u16* p) {
    u32x4 u = *(const u32x4*)p;
    return __builtin_bit_cast(bf16x8, u);
}

// ---- fp32 -> bf16 convert (vec4) ----
__global__ __launch_bounds__(256) void cvt_f32_bf16(const float* __restrict__ in,
                                                    u16* __restrict__ out, int n4) {
    int i = blockIdx.x * 256 + threadIdx.x;
    if (i < n4) {
        float4 v = ((const float4*)in)[i];
        ushort4 o;
        o.x = f2bf(v.x); o.y = f2bf(v.y); o.z = f2bf(v.z); o.w = f2bf(v.w);
        ((ushort4*)out)[i] = o;
    }
}

// ---- shared 128x128xBK32 bf16 MFMA GEMM, Y = A @ W^T + bias, epilogue by mode ----
// mode 0: gauge   -> out_bf = bf16( xres + 0.1*((acc+bias)*theta) )
// mode 1: qkv     -> scatter to q[B,H,N,D], k[B,H,N,D], vT[B,H,D,N] (bf16)
// mode 2: proj    -> out_f = acc + bias (fp32)
#define GLDS 40
__global__ __launch_bounds__(256) void gemm_bt(
    int mode, int ncols,
    const u16* __restrict__ A,      // [4096,1024] bf16
    const u16* __restrict__ W,      // [ncols,1024] bf16 (row-major: K contiguous)
    const float* __restrict__ bias, // [ncols]
    const float* __restrict__ xres, // mode0: [4096,1024] fp32
    const float* __restrict__ theta,// mode0: [1024] fp32
    u16* __restrict__ out_bf,       // mode0
    u16* __restrict__ qo, u16* __restrict__ ko, u16* __restrict__ vTo, // mode1
    float* __restrict__ out_f)      // mode2
{
    __shared__ alignas(16) u16 As[128 * GLDS];
    __shared__ alignas(16) u16 Bs[128 * GLDS];
    const int tid  = threadIdx.x;
    const int wave = tid >> 6, lane = tid & 63;
    const int lquad = lane >> 4, lcol = lane & 15;
    const int wr = (wave >> 1) * 64, wc = (wave & 1) * 64;
    const int rowb = blockIdx.x * 128, colb = blockIdx.y * 128;
    const int sr = tid >> 2, sc = (tid & 3) * 8;

    f32x4 zero4 = {0.f, 0.f, 0.f, 0.f};
    f32x4 acc[4][4];
#pragma unroll
    for (int i = 0; i < 4; i++)
#pragma unroll
        for (int j = 0; j < 4; j++) acc[i][j] = zero4;

    const u16* Ap = A + (size_t)(rowb + sr) * 1024 + sc;
    const u16* Wp = W + (size_t)(colb + sr) * 1024 + sc;

    for (int k0 = 0; k0 < 1024; k0 += 32) {
        u32x4 a0 = *(const u32x4*)(Ap + k0);
        u32x4 a1 = *(const u32x4*)(Ap + 64 * 1024 + k0);
        u32x4 b0 = *(const u32x4*)(Wp + k0);
        u32x4 b1 = *(const u32x4*)(Wp + 64 * 1024 + k0);
        __syncthreads();   // previous iter's frag reads complete
        *(u32x4*)(As + sr * GLDS + sc)        = a0;
        *(u32x4*)(As + (sr + 64) * GLDS + sc) = a1;
        *(u32x4*)(Bs + sr * GLDS + sc)        = b0;
        *(u32x4*)(Bs + (sr + 64) * GLDS + sc) = b1;
        __syncthreads();
        bf16x8 af[4], bfr[4];
#pragma unroll
        for (int t = 0; t < 4; t++) af[t]  = ld_frag(As + (wr + t * 16 + lcol) * GLDS + lquad * 8);
#pragma unroll
        for (int t = 0; t < 4; t++) bfr[t] = ld_frag(Bs + (wc + t * 16 + lcol) * GLDS + lquad * 8);
#pragma unroll
        for (int i = 0; i < 4; i++)
#pragma unroll
            for (int j = 0; j < 4; j++)
                acc[i][j] = __builtin_amdgcn_mfma_f32_16x16x32_bf16(af[i], bfr[j], acc[i][j], 0, 0, 0);
    }

    // epilogue: C/D layout col=lane&15, row=(lane>>4)*4+reg
#pragma unroll
    for (int i = 0; i < 4; i++) {
#pragma unroll
        for (int j = 0; j < 4; j++) {
            int gcol = colb + wc + j * 16 + lcol;
            float bsv = bias[gcol];
#pragma unroll
            for (int r = 0; r < 4; r++) {
                int grow = rowb + wr + i * 16 + lquad * 4 + r;
                float val = acc[i][j][r] + bsv;
                if (mode == 0) {
                    size_t idx = (size_t)grow * 1024 + gcol;
                    float xg = xres[idx] + 0.1f * (val * theta[gcol]);
                    out_bf[idx] = f2bf(xg);
                } else if (mode == 1) {
                    int three = gcol >> 10, rem = gcol & 1023;
                    int h = rem >> 6, d = rem & 63;
                    int b = grow >> 11, nn = grow & 2047;
                    int bh = b * 16 + h;
                    u16 bv = f2bf(val);
                    if (three == 0)      qo[((size_t)bh * 2048 + nn) * 64 + d] = bv;
                    else if (three == 1) ko[((size_t)bh * 2048 + nn) * 64 + d] = bv;
                    else                 vTo[((size_t)bh * 64 + d) * 2048 + nn] = bv;
                } else {
                    out_f[(size_t)grow * 1024 + gcol] = val;
                }
            }
        }
    }
}

// ---- flash attention: per block 128 Q rows (32/wave), K-tiles of 64 ----
#define AT_LDK 72
__device__ __forceinline__ float rowmax16(float v) {
    v = fmaxf(v, __shfl_xor(v, 1, 16));
    v = fmaxf(v, __shfl_xor(v, 2, 16));
    v = fmaxf(v, __shfl_xor(v, 4, 16));
    v = fmaxf(v, __shfl_xor(v, 8, 16));
    return v;
}
__device__ __forceinline__ float rowsum16(float v) {
    v += __shfl_xor(v, 1, 16);
    v += __shfl_xor(v, 2, 16);
    v += __shfl_xor(v, 4, 16);
    v += __shfl_xor(v, 8, 16);
    return v;
}

__global__ __launch_bounds__(256) void attn_kernel(
    const u16* __restrict__ q,   // [B*H, N, D] bf16
    const u16* __restrict__ k,   // [B*H, N, D] bf16
    const u16* __restrict__ vT,  // [B*H, D, N] bf16
    u16* __restrict__ attnout)   // [B, N, H*D] bf16
{
    __shared__ alignas(16) u16 Ks[64 * AT_LDK];
    __shared__ alignas(16) u16 Vs[64 * AT_LDK];
    __shared__ alignas(16) u16 Ps[4][32 * AT_LDK];

    const int tid  = threadIdx.x;
    const int wave = tid >> 6, lane = tid & 63;
    const int lquad = lane >> 4, lcol = lane & 15;
    const int bh   = blockIdx.y;
    const int row0 = blockIdx.x * 128 + wave * 32;
    const float scale_ = 0.125f;  // 1/sqrt(64)

    // Q frags (A layout: m=lane&15, k=quad*8+j), resident for whole loop
    bf16x8 qf[2][2];
#pragma unroll
    for (int mt = 0; mt < 2; mt++)
#pragma unroll
        for (int ks = 0; ks < 2; ks++)
            qf[mt][ks] = ld_frag(q + ((size_t)bh * 2048 + row0 + mt * 16 + lcol) * 64 + ks * 32 + lquad * 8);

    float mrun[2][4], lrun[2][4];
    f32x4 zero4 = {0.f, 0.f, 0.f, 0.f};
    f32x4 oacc[2][4];
#pragma unroll
    for (int mt = 0; mt < 2; mt++) {
#pragma unroll
        for (int r = 0; r < 4; r++) { mrun[mt][r] = -1e30f; lrun[mt][r] = 0.f; }
#pragma unroll
        for (int nt = 0; nt < 4; nt++) oacc[mt][nt] = zero4;
    }

    const int jr = tid >> 3, dc = (tid & 7) * 8;  // staging ids (2 vecs per thread)

    for (int j0 = 0; j0 < 2048; j0 += 64) {
        __syncthreads();
        *(u32x4*)(Ks + jr * AT_LDK + dc)        = *(const u32x4*)(k + ((size_t)bh * 2048 + j0 + jr) * 64 + dc);
        *(u32x4*)(Ks + (jr + 32) * AT_LDK + dc) = *(const u32x4*)(k + ((size_t)bh * 2048 + j0 + jr + 32) * 64 + dc);
        *(u32x4*)(Vs + jr * AT_LDK + dc)        = *(const u32x4*)(vT + ((size_t)bh * 64 + jr) * 2048 + j0 + dc);
        *(u32x4*)(Vs + (jr + 32) * AT_LDK + dc) = *(const u32x4*)(vT + ((size_t)bh * 64 + jr + 32) * 2048 + j0 + dc);
        __syncthreads();

        // S = (Q K^T) * scale ; S frag: rows=Q rows, cols=j
        f32x4 sacc[2][4];
#pragma unroll
        for (int mt = 0; mt < 2; mt++)
#pragma unroll
            for (int nt = 0; nt < 4; nt++) sacc[mt][nt] = zero4;
#pragma unroll
        for (int nt = 0; nt < 4; nt++) {
            bf16x8 kfa = ld_frag(Ks + (nt * 16 + lcol) * AT_LDK + lquad * 8);
            bf16x8 kfb = ld_frag(Ks + (nt * 16 + lcol) * AT_LDK + 32 + lquad * 8);
#pragma unroll
            for (int mt = 0; mt < 2; mt++) {
                sacc[mt][nt] = __builtin_amdgcn_mfma_f32_16x16x32_bf16(qf[mt][0], kfa, sacc[mt][nt], 0, 0, 0);
                sacc[mt][nt] = __builtin_amdgcn_mfma_f32_16x16x32_bf16(qf[mt][1], kfb, sacc[mt][nt], 0, 0, 0);
            }
        }

        // online softmax (per row; rows live in 16-lane groups)
#pragma unroll
        for (int mt = 0; mt < 2; mt++) {
#pragma unroll
            for (int r = 0; r < 4; r++) {
                float s0 = sacc[mt][0][r] * scale_;
                float s1 = sacc[mt][1][r] * scale_;
                float s2 = sacc[mt][2][r] * scale_;
                float s3 = sacc[mt][3][r] * scale_;
                float vmax = rowmax16(fmaxf(fmaxf(s0, s1), fmaxf(s2, s3)));
                float mold = mrun[mt][r];
                float mnew = fmaxf(mold, vmax);
                float alpha = __expf(mold - mnew);
                mrun[mt][r] = mnew;
                float p0 = __expf(s0 - mnew), p1 = __expf(s1 - mnew);
                float p2 = __expf(s2 - mnew), p3 = __expf(s3 - mnew);
                float rs = rowsum16(p0 + p1 + p2 + p3);
                lrun[mt][r] = lrun[mt][r] * alpha + rs;
                oacc[mt][0][r] *= alpha; oacc[mt][1][r] *= alpha;
                oacc[mt][2][r] *= alpha; oacc[mt][3][r] *= alpha;
                int prow = mt * 16 + lquad * 4 + r;
                Ps[wave][prow * AT_LDK +  0 + lcol] = f2bf(p0);
                Ps[wave][prow * AT_LDK + 16 + lcol] = f2bf(p1);
                Ps[wave][prow * AT_LDK + 32 + lcol] = f2bf(p2);
                Ps[wave][prow * AT_LDK + 48 + lcol] = f2bf(p3);
            }
        }

        // O += P @ V  (P via LDS round-trip to A-layout; V^T rows give B-layout)
        bf16x8 pf[2][2];
#pragma unroll
        for (int mt = 0; mt < 2; mt++)
#pragma unroll
            for (int ks2 = 0; ks2 < 2; ks2++)
                pf[mt][ks2] = ld_frag(&Ps[wave][(mt * 16 + lcol) * AT_LDK + ks2 * 32 + lquad * 8]);
#pragma unroll
        for (int nt = 0; nt < 4; nt++) {
#pragma unroll
            for (int ks2 = 0; ks2 < 2; ks2++) {
                bf16x8 vf = ld_frag(Vs + (nt * 16 + lcol) * AT_LDK + ks2 * 32 + lquad * 8);
                oacc[0][nt] = __builtin_amdgcn_mfma_f32_16x16x32_bf16(pf[0][ks2], vf, oacc[0][nt], 0, 0, 0);
                oacc[1][nt] = __builtin_amdgcn_mfma_f32_16x16x32_bf16(pf[1][ks2], vf, oacc[1][nt], 0, 0, 0);
            }
        }
    }

    // normalize + write attnout[b, n, h*64+d]
    const int b = bh >> 4, h = bh & 15;
#pragma unroll
    for (int mt = 0; mt < 2; mt++) {
#pragma unroll
        for (int r = 0; r < 4; r++) {
            float inv = 1.0f / lrun[mt][r];
            int n = row0 + mt * 16 + lquad * 4 + r;
            size_t base = ((size_t)b * 2048 + n) * 1024 + h * 64;
#pragma unroll
            for (int nt = 0; nt < 4; nt++)
                attnout[base + nt * 16 + lcol] = f2bf(oacc[mt][nt][r] * inv);
        }
    }
}

extern "C" void kernel_launch(void* const* d_in, const int* in_sizes, int n_in,
                              void* d_out, int out_size, void* d_ws, size_t ws_size,
                              hipStream_t stream) {
    const float* x     = (const float*)d_in[0];
    const float* theta = (const float*)d_in[1];
    const float* Wg    = (const float*)d_in[2];
    const float* bg    = (const float*)d_in[3];
    const float* Wqkv  = (const float*)d_in[4];
    const float* bqkv  = (const float*)d_in[5];
    const float* Wproj = (const float*)d_in[6];
    const float* bproj = (const float*)d_in[7];
    float* out = (float*)d_out;

    // workspace layout (58 MB total)
    unsigned char* ws = (unsigned char*)d_ws;
    const size_t MB = 1ull << 20;
    u16* x_bf     = (u16*)(ws + 0);        // 8 MB  [4096,1024]
    u16* Wg_bf    = (u16*)(ws + 8 * MB);   // 2 MB  [1024,1024]
    u16* Wqkv_bf  = (u16*)(ws + 10 * MB);  // 6 MB  [3072,1024]
    u16* Wproj_bf = (u16*)(ws + 16 * MB);  // 2 MB  [1024,1024]
    u16* xg_bf    = (u16*)(ws + 18 * MB);  // 8 MB  [4096,1024]
    u16* q_bf     = (u16*)(ws + 26 * MB);  // 8 MB  [32,2048,64]
    u16* k_bf     = (u16*)(ws + 34 * MB);  // 8 MB  [32,2048,64]
    u16* vT_bf    = (u16*)(ws + 42 * MB);  // 8 MB  [32,64,2048]
    u16* ao_bf    = (u16*)(ws + 50 * MB);  // 8 MB  [4096,1024]

    dim3 blk(256);
    // converts (element counts are exact multiples of 1024)
    cvt_f32_bf16<<<4096, blk, 0, stream>>>(x,     x_bf,     1048576);
    cvt_f32_bf16<<<1024, blk, 0, stream>>>(Wg,    Wg_bf,    262144);
    cvt_f32_bf16<<<3072, blk, 0, stream>>>(Wqkv,  Wqkv_bf,  786432);
    cvt_f32_bf16<<<1024, blk, 0, stream>>>(Wproj, Wproj_bf, 262144);

    // gauge: xg = x + 0.1*((x@Wg^T + bg)*theta)
    gemm_bt<<<dim3(32, 8), blk, 0, stream>>>(0, 1024, x_bf, Wg_bf, bg,
                                             x, theta, xg_bf,
                                             nullptr, nullptr, nullptr, nullptr);
    // qkv: scatter q,k,[vT]
    gemm_bt<<<dim3(32, 24), blk, 0, stream>>>(1, 3072, xg_bf, Wqkv_bf, bqkv,
                                              nullptr, nullptr, nullptr,
                                              q_bf, k_bf, vT_bf, nullptr);
    // attention
    attn_kernel<<<dim3(16, 32), blk, 0, stream>>>(q_bf, k_bf, vT_bf, ao_bf);
    // proj: out = ao @ Wproj^T + bproj
    gemm_bt<<<dim3(32, 8), blk, 0, stream>>>(2, 1024, ao_bf, Wproj_bf, bproj,
                                             nullptr, nullptr, nullptr,
                                             nullptr, nullptr, nullptr, out);
}

// Round 3
// 271.465 us; speedup vs baseline: 1.3362x; 1.3362x over previous
//
#include <hip/hip_runtime.h>
#include <stdint.h>

// ---- types ----
typedef __bf16 bf16x8 __attribute__((ext_vector_type(8)));
typedef float  f32x4  __attribute__((ext_vector_type(4)));
typedef unsigned int u32x4 __attribute__((ext_vector_type(4)));
typedef unsigned short u16;

__device__ __forceinline__ u16 f2bf(float f) {
    union { float f; unsigned u; } v; v.f = f;
    unsigned r = v.u + 0x7fffu + ((v.u >> 16) & 1u);
    return (u16)(r >> 16);
}

__device__ __forceinline__ bf16x8 ld_frag(const u16* p) {
    u32x4 u = *(const u32x4*)p;
    return __builtin_bit_cast(bf16x8, u);
}

// async global->LDS, 16B per lane; LDS dest = wave-uniform base + lane*16
__device__ __forceinline__ void gload16(const u16* g, u16* l) {
    __builtin_amdgcn_global_load_lds(
        (__attribute__((address_space(1))) void*)g,
        (__attribute__((address_space(3))) void*)l,
        16, 0, 0);
}

// ---- fp32 -> bf16 convert (vec4) ----
__global__ __launch_bounds__(256) void cvt_f32_bf16(const float* __restrict__ in,
                                                    u16* __restrict__ out, int n4) {
    int i = blockIdx.x * 256 + threadIdx.x;
    if (i < n4) {
        float4 v = ((const float4*)in)[i];
        ushort4 o;
        o.x = f2bf(v.x); o.y = f2bf(v.y); o.z = f2bf(v.z); o.w = f2bf(v.w);
        ((ushort4*)out)[i] = o;
    }
}

// ---- 128x128xBK32 bf16 MFMA GEMM, Y = A @ W^T + bias, global_load_lds staging ----
// mode 0: gauge -> out_bf = bf16( xres + 0.1*((acc+bias)*theta) )
// mode 1: qkv   -> scatter q[BH,N,D], k[BH,N,D], vT[BH,D,N] (bf16, vT packed x4)
// mode 2: proj  -> out_f = acc + bias (fp32)
__global__ __launch_bounds__(256) void gemm_bt(
    int mode, int ncols,
    const u16* __restrict__ A,      // [4096,1024] bf16
    const u16* __restrict__ W,      // [ncols,1024] bf16 (K contiguous)
    const float* __restrict__ bias,
    const float* __restrict__ xres,
    const float* __restrict__ theta,
    u16* __restrict__ out_bf,
    u16* __restrict__ qo, u16* __restrict__ ko, u16* __restrict__ vTo,
    float* __restrict__ out_f)
{
    __shared__ alignas(16) u16 As[128 * 32];   // [row][32] u16, stride 64B (no pad!)
    __shared__ alignas(16) u16 Bs[128 * 32];
    const int tid  = threadIdx.x;
    const int wave = tid >> 6, lane = tid & 63;
    const int lquad = lane >> 4, lcol = lane & 15;
    const int wr = (wave >> 1) * 64, wc = (wave & 1) * 64;
    const int rowb = blockIdx.x * 128, colb = blockIdx.y * 128;

    // staging roles: waves 0,1 -> A halves; waves 2,3 -> W halves
    const u16* src  = (wave & 2) ? W : A;
    const int  rbase = (wave & 2) ? colb : rowb;
    u16* dst = ((wave & 2) ? Bs : As) + (wave & 1) * 64 * 32;
    const u16* gsrc = src + (size_t)(rbase + (wave & 1) * 64 + (lane >> 2)) * 1024 + (lane & 3) * 8;

    f32x4 zero4 = {0.f, 0.f, 0.f, 0.f};
    f32x4 acc[4][4];
#pragma unroll
    for (int i = 0; i < 4; i++)
#pragma unroll
        for (int j = 0; j < 4; j++) acc[i][j] = zero4;

    for (int k0 = 0; k0 < 1024; k0 += 32) {
        __syncthreads();   // prev frag reads done before overwrite
#pragma unroll
        for (int i = 0; i < 4; i++)
            gload16(gsrc + (size_t)(i * 16) * 1024 + k0, dst + i * 16 * 32);
        __syncthreads();   // drains vmcnt(0) at barrier
        bf16x8 af[4], bfr[4];
#pragma unroll
        for (int t = 0; t < 4; t++) af[t]  = ld_frag(As + (wr + t * 16 + lcol) * 32 + lquad * 8);
#pragma unroll
        for (int t = 0; t < 4; t++) bfr[t] = ld_frag(Bs + (wc + t * 16 + lcol) * 32 + lquad * 8);
#pragma unroll
        for (int i = 0; i < 4; i++)
#pragma unroll
            for (int j = 0; j < 4; j++)
                acc[i][j] = __builtin_amdgcn_mfma_f32_16x16x32_bf16(af[i], bfr[j], acc[i][j], 0, 0, 0);
    }

    // epilogue: C/D layout col=lane&15, row=(lane>>4)*4+reg
#pragma unroll
    for (int i = 0; i < 4; i++) {
#pragma unroll
        for (int j = 0; j < 4; j++) {
            int gcol = colb + wc + j * 16 + lcol;
            float bsv = bias[gcol];
            int grow0 = rowb + wr + i * 16 + lquad * 4;
            if (mode == 0) {
#pragma unroll
                for (int r = 0; r < 4; r++) {
                    size_t idx = (size_t)(grow0 + r) * 1024 + gcol;
                    float val = acc[i][j][r] + bsv;
                    out_bf[idx] = f2bf(xres[idx] + 0.1f * (val * theta[gcol]));
                }
            } else if (mode == 1) {
                int three = gcol >> 10, rem = gcol & 1023;
                int h = rem >> 6, d = rem & 63;
                int b = grow0 >> 11, nn = grow0 & 2047;
                int bh = b * 16 + h;
                if (three == 2) {
                    ushort4 o;
                    o.x = f2bf(acc[i][j][0] + bsv);
                    o.y = f2bf(acc[i][j][1] + bsv);
                    o.z = f2bf(acc[i][j][2] + bsv);
                    o.w = f2bf(acc[i][j][3] + bsv);
                    *(ushort4*)(vTo + ((size_t)bh * 64 + d) * 2048 + nn) = o;
                } else {
                    u16* dstp = (three == 0) ? qo : ko;
#pragma unroll
                    for (int r = 0; r < 4; r++)
                        dstp[((size_t)bh * 2048 + nn + r) * 64 + d] = f2bf(acc[i][j][r] + bsv);
                }
            } else {
#pragma unroll
                for (int r = 0; r < 4; r++)
                    out_f[(size_t)(grow0 + r) * 1024 + gcol] = acc[i][j][r] + bsv;
            }
        }
    }
}

// ---- flash attention, transposed: S^T = K Q^T, O^T = V^T P^T ----
// block: 4 waves x 16 q-rows = 64 q-rows; j-tile 64; grid (32, 32)
#define PS_LD 72
__global__ __launch_bounds__(256) void attn_kernel(
    const u16* __restrict__ q,   // [B*H, N, D]
    const u16* __restrict__ k,   // [B*H, N, D]
    const u16* __restrict__ vT,  // [B*H, D, N]
    u16* __restrict__ attnout)   // [B, N, H*D]
{
    __shared__ alignas(16) u16 Ks[2 * 64 * 32];   // [db][j][32]  (d split, stride 64B)
    __shared__ alignas(16) u16 Vs[2 * 64 * 32];   // [jb][d][32]  (j split)
    __shared__ alignas(16) u16 Ps[4][16 * PS_LD]; // per-wave P as [q][j]

    const int tid  = threadIdx.x;
    const int wave = tid >> 6, lane = tid & 63;
    const int lquad = lane >> 4, lcol = lane & 15;
    const int bh   = blockIdx.y;
    const int row0 = blockIdx.x * 64 + wave * 16;
    const float csc = 0.18033688011112042f;  // (1/sqrt(64)) * log2(e)

    // Q as B-operand: n=lcol (q-row), k=d
    bf16x8 qf[2];
#pragma unroll
    for (int db = 0; db < 2; db++)
        qf[db] = ld_frag(q + ((size_t)bh * 2048 + row0 + lcol) * 64 + db * 32 + lquad * 8);

    float mrun = -1e30f, lrun = 0.f;
    f32x4 zero4 = {0.f, 0.f, 0.f, 0.f};
    f32x4 oacc[4];   // O^T: row d = dt*16 + lquad*4 + r, col q = lcol
#pragma unroll
    for (int dt = 0; dt < 4; dt++) oacc[dt] = zero4;

    // staging roles: wave 0,1 -> K (db 0,1); wave 2,3 -> V^T (jb 0,1)
    const int sb = wave & 1;
    const int srow = lane >> 2, scol = (lane & 3) * 8;
    const u16* gK = k  + ((size_t)bh * 2048 + srow) * 64 + sb * 32 + scol;
    const u16* gV = vT + ((size_t)bh * 64 + srow) * 2048 + sb * 32 + scol;
    u16* ldst = ((wave & 2) ? Vs : Ks) + sb * 64 * 32;

    for (int j0 = 0; j0 < 2048; j0 += 64) {
        __syncthreads();
        if ((wave & 2) == 0) {
#pragma unroll
            for (int i = 0; i < 4; i++)
                gload16(gK + (size_t)(j0 + i * 16) * 64, ldst + i * 16 * 32);
        } else {
#pragma unroll
            for (int i = 0; i < 4; i++)
                gload16(gV + (size_t)(i * 16) * 2048 + j0, ldst + i * 16 * 32);
        }
        __syncthreads();   // drains vmcnt at barrier

        // S^T = K Q^T : rows j (4 frags), col q = lcol
        f32x4 sacc[4];
#pragma unroll
        for (int jt = 0; jt < 4; jt++) sacc[jt] = zero4;
#pragma unroll
        for (int jt = 0; jt < 4; jt++)
#pragma unroll
            for (int db = 0; db < 2; db++) {
                bf16x8 kf = ld_frag(Ks + db * 64 * 32 + (jt * 16 + lcol) * 32 + lquad * 8);
                sacc[jt] = __builtin_amdgcn_mfma_f32_16x16x32_bf16(kf, qf[db], sacc[jt], 0, 0, 0);
            }

        // softmax over j: 16 in-lane values + 2 cross-quad shuffles
        float t[4][4];
        float mx = -1e30f;
#pragma unroll
        for (int jt = 0; jt < 4; jt++)
#pragma unroll
            for (int r = 0; r < 4; r++) {
                t[jt][r] = sacc[jt][r] * csc;
                mx = fmaxf(mx, t[jt][r]);
            }
        mx = fmaxf(mx, __shfl_xor(mx, 16, 64));
        mx = fmaxf(mx, __shfl_xor(mx, 32, 64));
        float mnew = fmaxf(mrun, mx);
        float alpha = __builtin_amdgcn_exp2f(mrun - mnew);
        mrun = mnew;
        float p[4][4];
        float rs = 0.f;
#pragma unroll
        for (int jt = 0; jt < 4; jt++)
#pragma unroll
            for (int r = 0; r < 4; r++) {
                p[jt][r] = __builtin_amdgcn_exp2f(t[jt][r] - mnew);
                rs += p[jt][r];
            }
        rs += __shfl_xor(rs, 16, 64);
        rs += __shfl_xor(rs, 32, 64);
        lrun = lrun * alpha + rs;
#pragma unroll
        for (int dt = 0; dt < 4; dt++) oacc[dt] *= alpha;

        // write P as [q][j] rows (q=lcol): packed b64 stores, conflict-free
#pragma unroll
        for (int jt = 0; jt < 4; jt++) {
            ushort4 o;
            o.x = f2bf(p[jt][0]); o.y = f2bf(p[jt][1]);
            o.z = f2bf(p[jt][2]); o.w = f2bf(p[jt][3]);
            *(ushort4*)(&Ps[wave][lcol * PS_LD + jt * 16 + lquad * 4]) = o;
        }

        // P^T as B-operand: n=lcol (q), k=j ; V^T as A-operand: m=d, k=j
        bf16x8 pf[2];
#pragma unroll
        for (int kb = 0; kb < 2; kb++)
            pf[kb] = ld_frag(&Ps[wave][lcol * PS_LD + kb * 32 + lquad * 8]);
#pragma unroll
        for (int dt = 0; dt < 4; dt++)
#pragma unroll
            for (int kb = 0; kb < 2; kb++) {
                bf16x8 vf = ld_frag(Vs + kb * 64 * 32 + (dt * 16 + lcol) * 32 + lquad * 8);
                oacc[dt] = __builtin_amdgcn_mfma_f32_16x16x32_bf16(vf, pf[kb], oacc[dt], 0, 0, 0);
            }
    }

    // epilogue: O^T[d][q]/l -> attnout[b, n=q, h*64+d], packed x4 along d
    float inv = 1.0f / lrun;
    const int b = bh >> 4, h = bh & 15;
    const int n = row0 + lcol;
    size_t base = ((size_t)b * 2048 + n) * 1024 + h * 64;
#pragma unroll
    for (int dt = 0; dt < 4; dt++) {
        ushort4 o;
        o.x = f2bf(oacc[dt][0] * inv); o.y = f2bf(oacc[dt][1] * inv);
        o.z = f2bf(oacc[dt][2] * inv); o.w = f2bf(oacc[dt][3] * inv);
        *(ushort4*)(attnout + base + dt * 16 + lquad * 4) = o;
    }
}

extern "C" void kernel_launch(void* const* d_in, const int* in_sizes, int n_in,
                              void* d_out, int out_size, void* d_ws, size_t ws_size,
                              hipStream_t stream) {
    const float* x     = (const float*)d_in[0];
    const float* theta = (const float*)d_in[1];
    const float* Wg    = (const float*)d_in[2];
    const float* bg    = (const float*)d_in[3];
    const float* Wqkv  = (const float*)d_in[4];
    const float* bqkv  = (const float*)d_in[5];
    const float* Wproj = (const float*)d_in[6];
    const float* bproj = (const float*)d_in[7];
    float* out = (float*)d_out;

    unsigned char* ws = (unsigned char*)d_ws;
    const size_t MB = 1ull << 20;
    u16* x_bf     = (u16*)(ws + 0);
    u16* Wg_bf    = (u16*)(ws + 8 * MB);
    u16* Wqkv_bf  = (u16*)(ws + 10 * MB);
    u16* Wproj_bf = (u16*)(ws + 16 * MB);
    u16* xg_bf    = (u16*)(ws + 18 * MB);
    u16* q_bf     = (u16*)(ws + 26 * MB);
    u16* k_bf     = (u16*)(ws + 34 * MB);
    u16* vT_bf    = (u16*)(ws + 42 * MB);
    u16* ao_bf    = (u16*)(ws + 50 * MB);

    dim3 blk(256);
    cvt_f32_bf16<<<4096, blk, 0, stream>>>(x,     x_bf,     1048576);
    cvt_f32_bf16<<<1024, blk, 0, stream>>>(Wg,    Wg_bf,    262144);
    cvt_f32_bf16<<<3072, blk, 0, stream>>>(Wqkv,  Wqkv_bf,  786432);
    cvt_f32_bf16<<<1024, blk, 0, stream>>>(Wproj, Wproj_bf, 262144);

    gemm_bt<<<dim3(32, 8), blk, 0, stream>>>(0, 1024, x_bf, Wg_bf, bg,
                                             x, theta, xg_bf,
                                             nullptr, nullptr, nullptr, nullptr);
    gemm_bt<<<dim3(32, 24), blk, 0, stream>>>(1, 3072, xg_bf, Wqkv_bf, bqkv,
                                              nullptr, nullptr, nullptr,
                                              q_bf, k_bf, vT_bf, nullptr);
    attn_kernel<<<dim3(32, 32), blk, 0, stream>>>(q_bf, k_bf, vT_bf, ao_bf);
    gemm_bt<<<dim3(32, 8), blk, 0, stream>>>(2, 1024, ao_bf, Wproj_bf, bproj,
                                             nullptr, nullptr, nullptr,
                                             nullptr, nullptr, nullptr, out);
}

// Round 4
// 259.769 us; speedup vs baseline: 1.3964x; 1.0450x over previous
//
#include <hip/hip_runtime.h>
#include <stdint.h>

// ---- types ----
typedef __bf16 bf16x8 __attribute__((ext_vector_type(8)));
typedef float  f32x4  __attribute__((ext_vector_type(4)));
typedef unsigned int u32x4 __attribute__((ext_vector_type(4)));
typedef unsigned short u16;

__device__ __forceinline__ u16 f2bf(float f) {
    union { float f; unsigned u; } v; v.f = f;
    unsigned r = v.u + 0x7fffu + ((v.u >> 16) & 1u);
    return (u16)(r >> 16);
}

// packed 2x f32 -> bf16 (RNE); [15:0]=a, [31:16]=b
__device__ __forceinline__ unsigned pk_bf16(float a, float b) {
#if __has_builtin(__builtin_amdgcn_cvt_pk_bf16_f32)
    typedef __bf16 bf16x2_t __attribute__((ext_vector_type(2)));
    bf16x2_t r = __builtin_amdgcn_cvt_pk_bf16_f32(a, b);
    return __builtin_bit_cast(unsigned, r);
#else
    return (unsigned)f2bf(a) | ((unsigned)f2bf(b) << 16);
#endif
}

__device__ __forceinline__ bf16x8 ld_frag(const u16* p) {
    u32x4 u = *(const u32x4*)p;
    return __builtin_bit_cast(bf16x8, u);
}

// async global->LDS, 16B per lane; LDS dest = wave-uniform base + lane*16
__device__ __forceinline__ void gload16(const u16* g, u16* l) {
    __builtin_amdgcn_global_load_lds(
        (__attribute__((address_space(1))) void*)g,
        (__attribute__((address_space(3))) void*)l,
        16, 0, 0);
}

#define ATT_CSC 0.18033688011112042f  // (1/sqrt(64)) * log2(e)

// ---- fp32 -> bf16 convert (vec4) ----
__global__ __launch_bounds__(256) void cvt_f32_bf16(const float* __restrict__ in,
                                                    u16* __restrict__ out, int n4) {
    int i = blockIdx.x * 256 + threadIdx.x;
    if (i < n4) {
        float4 v = ((const float4*)in)[i];
        uint2 o;
        o.x = pk_bf16(v.x, v.y);
        o.y = pk_bf16(v.z, v.w);
        ((uint2*)out)[i] = o;
    }
}

// ---- 128x128xBK32 bf16 MFMA GEMM, Y = A @ W^T + bias, global_load_lds staging ----
// mode 0: gauge -> out_bf = bf16( xres + 0.1*((acc+bias)*theta) )
// mode 1: qkv   -> scatter q[BH,N,D] (pre-scaled by ATT_CSC), k[BH,N,D], vT[BH,D,N]
// mode 2: proj  -> out_f = acc + bias (fp32)
__global__ __launch_bounds__(256) void gemm_bt(
    int mode, int ncols,
    const u16* __restrict__ A,      // [4096,1024] bf16
    const u16* __restrict__ W,      // [ncols,1024] bf16 (K contiguous)
    const float* __restrict__ bias,
    const float* __restrict__ xres,
    const float* __restrict__ theta,
    u16* __restrict__ out_bf,
    u16* __restrict__ qo, u16* __restrict__ ko, u16* __restrict__ vTo,
    float* __restrict__ out_f)
{
    __shared__ alignas(16) u16 As[128 * 32];   // [row][32] u16, stride 64B (no pad!)
    __shared__ alignas(16) u16 Bs[128 * 32];
    const int tid  = threadIdx.x;
    const int wave = tid >> 6, lane = tid & 63;
    const int lquad = lane >> 4, lcol = lane & 15;
    const int wr = (wave >> 1) * 64, wc = (wave & 1) * 64;
    const int rowb = blockIdx.x * 128, colb = blockIdx.y * 128;

    // staging roles: waves 0,1 -> A halves; waves 2,3 -> W halves
    const u16* src  = (wave & 2) ? W : A;
    const int  rbase = (wave & 2) ? colb : rowb;
    u16* dst = ((wave & 2) ? Bs : As) + (wave & 1) * 64 * 32;
    const u16* gsrc = src + (size_t)(rbase + (wave & 1) * 64 + (lane >> 2)) * 1024 + (lane & 3) * 8;

    f32x4 zero4 = {0.f, 0.f, 0.f, 0.f};
    f32x4 acc[4][4];
#pragma unroll
    for (int i = 0; i < 4; i++)
#pragma unroll
        for (int j = 0; j < 4; j++) acc[i][j] = zero4;

    for (int k0 = 0; k0 < 1024; k0 += 32) {
        __syncthreads();
#pragma unroll
        for (int i = 0; i < 4; i++)
            gload16(gsrc + (size_t)(i * 16) * 1024 + k0, dst + i * 16 * 32);
        __syncthreads();
        bf16x8 af[4], bfr[4];
#pragma unroll
        for (int t = 0; t < 4; t++) af[t]  = ld_frag(As + (wr + t * 16 + lcol) * 32 + lquad * 8);
#pragma unroll
        for (int t = 0; t < 4; t++) bfr[t] = ld_frag(Bs + (wc + t * 16 + lcol) * 32 + lquad * 8);
#pragma unroll
        for (int i = 0; i < 4; i++)
#pragma unroll
            for (int j = 0; j < 4; j++)
                acc[i][j] = __builtin_amdgcn_mfma_f32_16x16x32_bf16(af[i], bfr[j], acc[i][j], 0, 0, 0);
    }

    // epilogue: C/D layout col=lane&15, row=(lane>>4)*4+reg
#pragma unroll
    for (int i = 0; i < 4; i++) {
#pragma unroll
        for (int j = 0; j < 4; j++) {
            int gcol = colb + wc + j * 16 + lcol;
            float bsv = bias[gcol];
            int grow0 = rowb + wr + i * 16 + lquad * 4;
            if (mode == 0) {
#pragma unroll
                for (int r = 0; r < 4; r++) {
                    size_t idx = (size_t)(grow0 + r) * 1024 + gcol;
                    float val = acc[i][j][r] + bsv;
                    out_bf[idx] = f2bf(xres[idx] + 0.1f * (val * theta[gcol]));
                }
            } else if (mode == 1) {
                int three = gcol >> 10, rem = gcol & 1023;
                int h = rem >> 6, d = rem & 63;
                int b = grow0 >> 11, nn = grow0 & 2047;
                int bh = b * 16 + h;
                if (three == 2) {
                    ushort4 o;
                    o.x = f2bf(acc[i][j][0] + bsv);
                    o.y = f2bf(acc[i][j][1] + bsv);
                    o.z = f2bf(acc[i][j][2] + bsv);
                    o.w = f2bf(acc[i][j][3] + bsv);
                    *(ushort4*)(vTo + ((size_t)bh * 64 + d) * 2048 + nn) = o;
                } else if (three == 0) {
#pragma unroll
                    for (int r = 0; r < 4; r++)
                        qo[((size_t)bh * 2048 + nn + r) * 64 + d] = f2bf((acc[i][j][r] + bsv) * ATT_CSC);
                } else {
#pragma unroll
                    for (int r = 0; r < 4; r++)
                        ko[((size_t)bh * 2048 + nn + r) * 64 + d] = f2bf(acc[i][j][r] + bsv);
                }
            } else {
#pragma unroll
                for (int r = 0; r < 4; r++)
                    out_f[(size_t)(grow0 + r) * 1024 + gcol] = acc[i][j][r] + bsv;
            }
        }
    }
}

// ---- flash attention, transposed, fixed-max softmax ----
// S^T = K Q'^T (q pre-scaled by csc), P = exp2(S^T), O^T = V^T P^T
// block: 4 waves x 32 q-rows = 128 q-rows; j-tile 64; grid (16, 32)
#define PS_LD 72
__global__ __launch_bounds__(256) void attn_kernel(
    const u16* __restrict__ q,   // [B*H, N, D] (pre-scaled)
    const u16* __restrict__ k,   // [B*H, N, D]
    const u16* __restrict__ vT,  // [B*H, D, N]
    u16* __restrict__ attnout)   // [B, N, H*D]
{
    __shared__ alignas(16) u16 Ks[2 * 64 * 32];   // [db][j][32]
    __shared__ alignas(16) u16 Vs[2 * 64 * 32];   // [jb][d][32]
    __shared__ alignas(16) u16 Ps[4][32 * PS_LD]; // per-wave P as [q][j]

    const int tid  = threadIdx.x;
    const int wave = tid >> 6, lane = tid & 63;
    const int lquad = lane >> 4, lcol = lane & 15;
    const int bh   = blockIdx.y;
    const int row0 = blockIdx.x * 128 + wave * 32;

    // Q as B-operand: n=lcol (q-row), k=d ; two q-halves of 16
    bf16x8 qf[2][2];
#pragma unroll
    for (int qh = 0; qh < 2; qh++)
#pragma unroll
        for (int db = 0; db < 2; db++)
            qf[qh][db] = ld_frag(q + ((size_t)bh * 2048 + row0 + qh * 16 + lcol) * 64 + db * 32 + lquad * 8);

    float lrun[2] = {0.f, 0.f};
    f32x4 zero4 = {0.f, 0.f, 0.f, 0.f};
    f32x4 oacc[2][4];   // [qh][dt] ; O^T row d = dt*16+lquad*4+r, col q
#pragma unroll
    for (int qh = 0; qh < 2; qh++)
#pragma unroll
        for (int dt = 0; dt < 4; dt++) oacc[qh][dt] = zero4;

    // staging roles: wave 0,1 -> K (db 0,1); wave 2,3 -> V^T (jb 0,1)
    const int sb = wave & 1;
    const int srow = lane >> 2, scol = (lane & 3) * 8;
    const u16* gK = k  + ((size_t)bh * 2048 + srow) * 64 + sb * 32 + scol;
    const u16* gV = vT + ((size_t)bh * 64 + srow) * 2048 + sb * 32 + scol;
    u16* ldst = ((wave & 2) ? Vs : Ks) + sb * 64 * 32;

    for (int j0 = 0; j0 < 2048; j0 += 64) {
        __syncthreads();
        if ((wave & 2) == 0) {
#pragma unroll
            for (int i = 0; i < 4; i++)
                gload16(gK + (size_t)(j0 + i * 16) * 64, ldst + i * 16 * 32);
        } else {
#pragma unroll
            for (int i = 0; i < 4; i++)
                gload16(gV + (size_t)(i * 16) * 2048 + j0, ldst + i * 16 * 32);
        }
        __syncthreads();

        // S^T = K Q'^T : rows j (4 frags), col q = lcol; kf reused across q-halves
        f32x4 sacc[2][4];
#pragma unroll
        for (int qh = 0; qh < 2; qh++)
#pragma unroll
            for (int jt = 0; jt < 4; jt++) sacc[qh][jt] = zero4;
#pragma unroll
        for (int jt = 0; jt < 4; jt++)
#pragma unroll
            for (int db = 0; db < 2; db++) {
                bf16x8 kf = ld_frag(Ks + db * 64 * 32 + (jt * 16 + lcol) * 32 + lquad * 8);
#pragma unroll
                for (int qh = 0; qh < 2; qh++)
                    sacc[qh][jt] = __builtin_amdgcn_mfma_f32_16x16x32_bf16(kf, qf[qh][db], sacc[qh][jt], 0, 0, 0);
            }

        // fixed-max softmax: p = exp2(s); in-lane partial row sums only
#pragma unroll
        for (int qh = 0; qh < 2; qh++) {
            float ls = 0.f;
#pragma unroll
            for (int jt = 0; jt < 4; jt++) {
                float p0 = __builtin_amdgcn_exp2f(sacc[qh][jt][0]);
                float p1 = __builtin_amdgcn_exp2f(sacc[qh][jt][1]);
                float p2 = __builtin_amdgcn_exp2f(sacc[qh][jt][2]);
                float p3 = __builtin_amdgcn_exp2f(sacc[qh][jt][3]);
                ls += (p0 + p1) + (p2 + p3);
                uint2 o;
                o.x = pk_bf16(p0, p1);
                o.y = pk_bf16(p2, p3);
                *(uint2*)(&Ps[wave][(qh * 16 + lcol) * PS_LD + jt * 16 + lquad * 4]) = o;
            }
            lrun[qh] += ls;
        }

        // O^T += V^T P^T ; vf reused across q-halves
        bf16x8 pf[2][2];
#pragma unroll
        for (int qh = 0; qh < 2; qh++)
#pragma unroll
            for (int kb = 0; kb < 2; kb++)
                pf[qh][kb] = ld_frag(&Ps[wave][(qh * 16 + lcol) * PS_LD + kb * 32 + lquad * 8]);
#pragma unroll
        for (int dt = 0; dt < 4; dt++)
#pragma unroll
            for (int kb = 0; kb < 2; kb++) {
                bf16x8 vf = ld_frag(Vs + kb * 64 * 32 + (dt * 16 + lcol) * 32 + lquad * 8);
#pragma unroll
                for (int qh = 0; qh < 2; qh++)
                    oacc[qh][dt] = __builtin_amdgcn_mfma_f32_16x16x32_bf16(vf, pf[qh][kb], oacc[qh][dt], 0, 0, 0);
            }
    }

    // epilogue: O^T[d][q]/l -> attnout[b, n=q, h*64+d]
    const int b = bh >> 4, h = bh & 15;
#pragma unroll
    for (int qh = 0; qh < 2; qh++) {
        float l = lrun[qh];
        l += __shfl_xor(l, 16, 64);
        l += __shfl_xor(l, 32, 64);
        float inv = 1.0f / l;
        const int n = row0 + qh * 16 + lcol;
        size_t base = ((size_t)b * 2048 + n) * 1024 + h * 64;
#pragma unroll
        for (int dt = 0; dt < 4; dt++) {
            uint2 o;
            o.x = pk_bf16(oacc[qh][dt][0] * inv, oacc[qh][dt][1] * inv);
            o.y = pk_bf16(oacc[qh][dt][2] * inv, oacc[qh][dt][3] * inv);
            *(uint2*)(attnout + base + dt * 16 + lquad * 4) = o;
        }
    }
}

extern "C" void kernel_launch(void* const* d_in, const int* in_sizes, int n_in,
                              void* d_out, int out_size, void* d_ws, size_t ws_size,
                              hipStream_t stream) {
    const float* x     = (const float*)d_in[0];
    const float* theta = (const float*)d_in[1];
    const float* Wg    = (const float*)d_in[2];
    const float* bg    = (const float*)d_in[3];
    const float* Wqkv  = (const float*)d_in[4];
    const float* bqkv  = (const float*)d_in[5];
    const float* Wproj = (const float*)d_in[6];
    const float* bproj = (const float*)d_in[7];
    float* out = (float*)d_out;

    unsigned char* ws = (unsigned char*)d_ws;
    const size_t MB = 1ull << 20;
    u16* x_bf     = (u16*)(ws + 0);
    u16* Wg_bf    = (u16*)(ws + 8 * MB);
    u16* Wqkv_bf  = (u16*)(ws + 10 * MB);
    u16* Wproj_bf = (u16*)(ws + 16 * MB);
    u16* xg_bf    = (u16*)(ws + 18 * MB);
    u16* q_bf     = (u16*)(ws + 26 * MB);
    u16* k_bf     = (u16*)(ws + 34 * MB);
    u16* vT_bf    = (u16*)(ws + 42 * MB);
    u16* ao_bf    = (u16*)(ws + 50 * MB);

    dim3 blk(256);
    cvt_f32_bf16<<<1024, blk, 0, stream>>>(x,     x_bf,     262144);
    cvt_f32_bf16<<<1024, blk, 0, stream>>>(Wg,    Wg_bf,    262144);
    cvt_f32_bf16<<<3072, blk, 0, stream>>>(Wqkv,  Wqkv_bf,  786432);
    cvt_f32_bf16<<<1024, blk, 0, stream>>>(Wproj, Wproj_bf, 262144);
    cvt_f32_bf16<<<3072, blk, 0, stream>>>(x + 1048576, x_bf + 1048576, 786432);

    gemm_bt<<<dim3(32, 8), blk, 0, stream>>>(0, 1024, x_bf, Wg_bf, bg,
                                             x, theta, xg_bf,
                                             nullptr, nullptr, nullptr, nullptr);
    gemm_bt<<<dim3(32, 24), blk, 0, stream>>>(1, 3072, xg_bf, Wqkv_bf, bqkv,
                                              nullptr, nullptr, nullptr,
                                              q_bf, k_bf, vT_bf, nullptr);
    attn_kernel<<<dim3(16, 32), blk, 0, stream>>>(q_bf, k_bf, vT_bf, ao_bf);
    gemm_bt<<<dim3(32, 8), blk, 0, stream>>>(2, 1024, ao_bf, Wproj_bf, bproj,
                                             nullptr, nullptr, nullptr,
                                             nullptr, nullptr, nullptr, out);
}